// Round 6
// baseline (1100.890 us; speedup 1.0000x reference)
//
#include <hip/hip_runtime.h>
#include <hip/hip_bf16.h>

// ---------------------------------------------------------------------------
// Problem constants (from reference)
// ---------------------------------------------------------------------------
#define HDIM 512
#define KA   128
#define VOC  32000
#define ANUMC 20
#define NSEQ 64
#define BATCH 32
#define TLEN 256
#define SLEN 32
#define ALEN 5
#define NB   2048          // NSEQ*BATCH
#define CIN  1664          // 3H + KA
#define G3H  1536
#define GB   64            // GRU persistent blocks

typedef __bf16 bf16;
typedef bf16 v8bf __attribute__((ext_vector_type(8)));
typedef float v4f __attribute__((ext_vector_type(4)));

#define DEV __device__ __forceinline__

DEV float sigmoidf_(float x) { return 1.f / (1.f + expf(-x)); }

DEV unsigned long long pack4bf(float a, float b, float c, float d) {
  bf16 b0 = (bf16)a, b1 = (bf16)b, b2 = (bf16)c, b3 = (bf16)d;
  return (unsigned long long)*(unsigned short*)&b0 |
         ((unsigned long long)*(unsigned short*)&b1 << 16) |
         ((unsigned long long)*(unsigned short*)&b2 << 32) |
         ((unsigned long long)*(unsigned short*)&b3 << 48);
}

// ---------------------------------------------------------------------------
// k_zero: zero the 64 dense GRU flags
// ---------------------------------------------------------------------------
__global__ void k_zero(int* bar) {
  if (threadIdx.x < GB) bar[threadIdx.x] = 0;
}

// ---------------------------------------------------------------------------
// k_init0/k_init1: aspect-add table for the fused GEMM epilogue.
// ---------------------------------------------------------------------------
__global__ void k_init0(float* addtab, int* colnz) {
  int i = blockIdx.x * 256 + threadIdx.x;
  if (i < VOC * ANUMC) addtab[i] = 0.f;
  if (i < VOC) colnz[i] = 0;
}
__global__ void k_init1(const int* __restrict__ ids, float* addtab, int* colnz) {
  for (int k = threadIdx.x; k < 2000; k += 256) {
    int j = ids[k];
    atomicAdd(addtab + (size_t)j * ANUMC + (k % ANUMC), 1.0f);
    colnz[j] = 1;
  }
}

// ---------------------------------------------------------------------------
// k_vec: small precomputations (see earlier rounds)
// ---------------------------------------------------------------------------
__global__ void k_vec(const float* __restrict__ attn_W, const float* __restrict__ attn_b,
                      const float* __restrict__ attn_v,
                      const float* __restrict__ attr_W, const float* __restrict__ attr_b,
                      const float* __restrict__ attr_v,
                      const float* __restrict__ enc4, const float* __restrict__ pW,
                      const float* __restrict__ pb, float* __restrict__ misc) {
  int tid = threadIdx.x;
  int blk = blockIdx.x;
  if (blk == 0) {
    for (int i = tid; i < 512; i += 256) {
      float s = 0.f;
      for (int j = 0; j < 512; ++j) s += attn_W[j * 1024 + i] * attn_v[j];
      misc[i] = s;
    }
  } else if (blk == 1) {
    for (int i = tid; i < 512; i += 256) {
      float s = 0.f;
      for (int j = 0; j < 512; ++j) s += attn_W[j * 1024 + 512 + i] * attn_v[j];
      misc[512 + i] = s;
    }
  } else if (blk == 2) {
    for (int i = tid; i < 512; i += 256) {
      float s = 0.f;
      for (int j = 0; j < 512; ++j) s += attr_W[j * 640 + i] * attr_v[j];
      misc[1024 + i] = s;
    }
  } else {
    for (int i = tid; i < 128; i += 256) {
      float s = 0.f;
      for (int j = 0; j < 512; ++j) s += attr_W[j * 640 + 512 + i] * attr_v[j];
      misc[1536 + i] = s;
    }
    if (tid == 128) {
      float s = 0.f;
      for (int j = 0; j < 512; ++j) s += attn_b[j] * attn_v[j];
      misc[1664] = s;
    }
    if (tid == 129) {
      float s = 0.f;
      for (int j = 0; j < 512; ++j) s += attr_b[j] * attr_v[j];
      misc[1665] = s;
    }
    for (int i = tid; i < BATCH * ANUMC; i += 256) {
      int b = i / ANUMC, j = i % ANUMC;
      float s = pb[j];
      for (int q = 0; q < ANUMC; ++q) s += pW[j * 40 + q] * enc4[b * ANUMC + q];
      for (int q = 0; q < ANUMC; ++q) s += pW[j * 40 + 20 + q] * enc4[BATCH * ANUMC + b * ANUMC + q];
      misc[1792 + i] = s;
    }
  }
}

// ---------------------------------------------------------------------------
// k_embcvt: embedding gather + fp32->bf16 conversions, x4 vectorized
// ---------------------------------------------------------------------------
__global__ void k_embcvt(const int* __restrict__ seq, const float* __restrict__ emb,
                         float* __restrict__ embedded, bf16* __restrict__ emb_bf,
                         const float* __restrict__ Wih, bf16* __restrict__ Wih_bf,
                         const float* __restrict__ cW, bf16* __restrict__ cW_bf,
                         const float* __restrict__ oW, bf16* __restrict__ oW_bf) {
  size_t i = ((size_t)blockIdx.x * 256 + threadIdx.x) * 4;
  const size_t s0 = 1048576, s1 = s0 + 786432, s2 = s1 + 851968, s3 = s2 + 16384000;
  if (i < s0) {
    int row = (int)(i >> 9), col = (int)(i & 511);
    float4 v = *(const float4*)(emb + (size_t)seq[row] * 512 + col);
    *(float4*)(embedded + i) = v;
    *(unsigned long long*)(emb_bf + i) = pack4bf(v.x, v.y, v.z, v.w);
  } else if (i < s1) {
    size_t j = i - s0;
    float4 v = *(const float4*)(Wih + j);
    *(unsigned long long*)(Wih_bf + j) = pack4bf(v.x, v.y, v.z, v.w);
  } else if (i < s2) {
    size_t j = i - s1;
    float4 v = *(const float4*)(cW + j);
    *(unsigned long long*)(cW_bf + j) = pack4bf(v.x, v.y, v.z, v.w);
  } else if (i < s3) {
    size_t j = i - s2;
    float4 v = *(const float4*)(oW + j);
    *(unsigned long long*)(oW_bf + j) = pack4bf(v.x, v.y, v.z, v.w);
  }
}

// ---------------------------------------------------------------------------
// k_c: c1[t*32+b] = enc1[t,b,:] . u1e ; c2 (enc2, u1e) ; c3 (enc3, u3e)
// ---------------------------------------------------------------------------
__global__ void k_c(const float* __restrict__ enc1, const float* __restrict__ enc2,
                    const float* __restrict__ enc3, float* __restrict__ misc) {
  int i = blockIdx.x * 256 + threadIdx.x;
  const float* u1e = misc + 512;
  const float* u3e = misc + 1536;
  if (i < 8192) {
    const float* row = enc1 + (size_t)i * 512;
    float s = 0.f;
#pragma unroll 4
    for (int j = 0; j < 512; j += 4) {
      float4 a = *(const float4*)(row + j);
      float4 u = *(const float4*)(u1e + j);
      s += a.x * u.x + a.y * u.y + a.z * u.z + a.w * u.w;
    }
    misc[2560 + i] = s;
  } else if (i < 8192 + 1024) {
    int k = i - 8192;
    const float* row = enc2 + (size_t)k * 512;
    float s = 0.f;
#pragma unroll 4
    for (int j = 0; j < 512; j += 4) {
      float4 a = *(const float4*)(row + j);
      float4 u = *(const float4*)(u1e + j);
      s += a.x * u.x + a.y * u.y + a.z * u.z + a.w * u.w;
    }
    misc[10752 + k] = s;
  } else if (i < 8192 + 1024 + 160) {
    int k = i - 9216;
    const float* row = enc3 + (size_t)k * 128;
    float s = 0.f;
#pragma unroll 4
    for (int j = 0; j < 128; j += 4) {
      float4 a = *(const float4*)(row + j);
      float4 u = *(const float4*)(u3e + j);
      s += a.x * u.x + a.y * u.y + a.z * u.z + a.w * u.w;
    }
    misc[11776 + k] = s;
  }
}

// ---------------------------------------------------------------------------
// Generic NT GEMM (round-3 tuned, unchanged)
// ---------------------------------------------------------------------------
template <int EPI>
__global__ __launch_bounds__(256, 2) void k_gemm_bt(const bf16* __restrict__ A,
                                                    const bf16* __restrict__ Bm,
                                                    const float* __restrict__ bias,
                                                    float* __restrict__ Cf, bf16* __restrict__ Cb,
                                                    int M, int Nn, int Kd,
                                                    const float* __restrict__ addtab,
                                                    const int* __restrict__ colnz,
                                                    const float* __restrict__ gate) {
  __shared__ __align__(16) unsigned short As[128 * 64];
  __shared__ __align__(16) unsigned short Bs[128 * 64];
  int tid = threadIdx.x;
  int nwg = gridDim.x;
  int cpx = nwg >> 3;
  int wgid = (blockIdx.x & 7) * cpx + (blockIdx.x >> 3);
  int MT = M >> 7;
  int m0 = (wgid % MT) << 7;
  int n0 = (wgid / MT) << 7;
  int lane = tid & 63;
  int wv = tid >> 6;
  int wm = wv & 1, wn = wv >> 1;
  int l15 = lane & 15, quad = lane >> 4;
  int l8r = lane >> 3;
  int lp = lane & 7;

  v4f acc[4][4];
#pragma unroll
  for (int i = 0; i < 4; ++i)
#pragma unroll
    for (int j = 0; j < 4; ++j) acc[i][j] = (v4f){0.f, 0.f, 0.f, 0.f};

  for (int kb = 0; kb < Kd; kb += 64) {
#pragma unroll
    for (int r = 0; r < 4; ++r) {
      int g = wv * 4 + r;
      int lr = g * 8 + l8r;
      int ca = (lp ^ (lr & 7)) * 8;
      __builtin_amdgcn_global_load_lds(
          (const __attribute__((address_space(1))) void*)(A + (size_t)(m0 + lr) * Kd + kb + ca),
          (__attribute__((address_space(3))) void*)((char*)As + g * 1024), 16, 0, 0);
      __builtin_amdgcn_global_load_lds(
          (const __attribute__((address_space(1))) void*)(Bm + (size_t)(n0 + lr) * Kd + kb + ca),
          (__attribute__((address_space(3))) void*)((char*)Bs + g * 1024), 16, 0, 0);
    }
    __syncthreads();
#pragma unroll
    for (int ks = 0; ks < 2; ++ks) {
      v8bf af[4], bfr[4];
      int c = ks * 4 + quad;
#pragma unroll
      for (int i = 0; i < 4; ++i) {
        int mr = wm * 64 + i * 16 + l15;
        af[i] = *(const v8bf*)((const char*)As + mr * 128 + ((c ^ (mr & 7)) << 4));
      }
#pragma unroll
      for (int j = 0; j < 4; ++j) {
        int nr = wn * 64 + j * 16 + l15;
        bfr[j] = *(const v8bf*)((const char*)Bs + nr * 128 + ((c ^ (nr & 7)) << 4));
      }
#pragma unroll
      for (int i = 0; i < 4; ++i)
#pragma unroll
        for (int j = 0; j < 4; ++j)
          acc[i][j] = __builtin_amdgcn_mfma_f32_16x16x32_bf16(af[i], bfr[j], acc[i][j], 0, 0, 0);
    }
    __syncthreads();
  }
#pragma unroll
  for (int i = 0; i < 4; ++i) {
    int gr0 = m0 + wm * 64 + i * 16 + quad * 4;
#pragma unroll
    for (int j = 0; j < 4; ++j) {
      int gc = n0 + wn * 64 + j * 16 + l15;
      float bs = bias[gc];
      if (EPI == 2) {
        int nz = colnz[gc];
        float ar[ANUMC];
        if (nz) {
#pragma unroll
          for (int a = 0; a < ANUMC; ++a) ar[a] = addtab[(size_t)gc * ANUMC + a];
        }
#pragma unroll
        for (int reg = 0; reg < 4; ++reg) {
          float v = acc[i][j][reg] + bs;
          if (nz) {
            const float* gr = gate + (size_t)(gr0 + reg) * ANUMC;
#pragma unroll
            for (int a = 0; a < ANUMC; ++a) v += ar[a] * gr[a];
          }
          Cf[(size_t)(gr0 + reg) * Nn + gc] = v;
        }
      } else {
#pragma unroll
        for (int reg = 0; reg < 4; ++reg) {
          float v = acc[i][j][reg] + bs;
          if (EPI == 1)
            Cb[(size_t)(gr0 + reg) * Nn + gc] = (bf16)tanhf(v);
          else
            Cf[(size_t)(gr0 + reg) * Nn + gc] = v;
        }
      }
    }
  }
}

// ---------------------------------------------------------------------------
// k_gru round-6: R3's verified skeleton (256 threads, wave0-only poll with
// s_sleep backoff + LDS go broadcast, 4-wave coalesced bulk load) combined
// with the strictly-cheaper R5 pieces:
//  - producer-major hx layout: block publishes 512B CONTIGUOUS (u64 idx =
//    blk*64 + batch*2 + half) -> 8-line burst, short vmcnt drain (was a
//    64-line scatter in R3).
//  - dense flags bar[64]: poll gather touches 4 lines (was 64), and only
//    ONE wave per block polls (R5's 4-wave no-sleep spin flooded the LLC
//    coherent path -> regression; reverted).
//  - rnn/concat global stores issued after the hnew barrier so their acks
//    overlap the exchange.
// Consumer: wave w instruction i reads producer p=w*16+i fully contiguous
// (64 lanes x 8B = that producer's 512B burst), then scatters to the
// XOR-swizzled hs rows (<=2 lanes/bank: free).
// Overwrite safety (distance 2) as in R3: publisher of h(t+1) observed all
// flags >= t, which implies every block consumed h(t-1) into LDS (data
// dependency of its LDS writes) before its step-(t-1) staging barrier.
// ---------------------------------------------------------------------------
__global__ __launch_bounds__(256) void k_gru(const float* __restrict__ gi,
                                             const float* __restrict__ Whh,
                                             const float* __restrict__ bhh,
                                             const float* __restrict__ lasth,
                                             float* __restrict__ rnn,
                                             bf16* __restrict__ concat_bf,
                                             unsigned long long* __restrict__ hx,
                                             int* __restrict__ bar) {
  struct SMEM {
    unsigned short hs[32 * 512];   // 32 KB, XOR-swizzled
    float gh[32 * 29];             // stride 29: conflict-free acc writes
    unsigned short hnew[256];      // 8B-aligned
    int go;                        // wave0 -> others handoff
  };
  __shared__ __align__(16) SMEM sm;
  int tid = threadIdx.x;
  int blk = blockIdx.x;
  int c0 = blk * 8;

  int lane = tid & 63;
  int w = tid >> 6;
  int l15 = lane & 15, quad = lane >> 4;
  int m0 = (w & 1) * 16;   // batch tile
  int n0 = (w >> 1) * 16;  // gate-row tile (rows >=24 phantom)

  if (tid == 0) sm.go = 0;

  // ---- Whh B-fragments -> registers (held across all 64 steps) ----
  v8bf breg[16];
  {
    int nr = n0 + l15;
    if (nr > 23) nr = 23;
    const float* wrow = Whh + (size_t)((nr >> 3) * 512 + c0 + (nr & 7)) * 512;
#pragma unroll
    for (int it = 0; it < 16; ++it) {
      int k0 = it * 32 + quad * 8;
      float4 x = *(const float4*)(wrow + k0);
      float4 y = *(const float4*)(wrow + k0 + 4);
      v8bf vv;
      vv[0] = (bf16)x.x; vv[1] = (bf16)x.y; vv[2] = (bf16)x.z; vv[3] = (bf16)x.w;
      vv[4] = (bf16)y.x; vv[5] = (bf16)y.y; vv[6] = (bf16)y.z; vv[7] = (bf16)y.w;
      breg[it] = vv;
    }
  }

  // ---- stage h(0) = lasth into hs (all threads) ----
#pragma unroll
  for (int rnd = 0; rnd < 8; ++rnd) {
    int ch = rnd * 256 + tid;
    int bb = ch >> 6, cc = ch & 63;
    const float* hp = lasth + bb * 512 + cc * 8;
    float4 x = *(const float4*)hp;
    float4 y = *(const float4*)(hp + 4);
    v8bf vv;
    vv[0] = (bf16)x.x; vv[1] = (bf16)x.y; vv[2] = (bf16)x.z; vv[3] = (bf16)x.w;
    vv[4] = (bf16)y.x; vv[5] = (bf16)y.y; vv[6] = (bf16)y.z; vv[7] = (bf16)y.w;
    *(v8bf*)((char*)sm.hs + bb * 1024 + ((cc ^ (bb & 7)) << 4)) = vv;
  }

  int cb = tid >> 3, j = tid & 7, c = c0 + j;
  float hprev = lasth[cb * 512 + c];
  float b_r = bhh[c], b_z = bhh[512 + c], b_n = bhh[1024 + c];
  __syncthreads();

  for (int t = 0; t < 64; ++t) {
    // prefetch this step's gi (independent of h; hides under MFMA)
    const float* gii = gi + ((size_t)t * 32 + cb) * G3H;
    float g_r = gii[c];
    float g_z = gii[512 + c];
    float g_n = gii[1024 + c];

    // ---- MFMA: gh[batch 32][gaterow 24]; A from LDS, B from registers ----
    {
      v4f acc0 = (v4f){0.f, 0.f, 0.f, 0.f};
      v4f acc1 = (v4f){0.f, 0.f, 0.f, 0.f};
      int mr = m0 + l15;
#pragma unroll
      for (int it = 0; it < 8; ++it) {
        {
          int ccx = it * 4 + quad;
          v8bf af = *(const v8bf*)((const char*)sm.hs + mr * 1024 + ((ccx ^ (mr & 7)) << 4));
          acc0 = __builtin_amdgcn_mfma_f32_16x16x32_bf16(af, breg[it], acc0, 0, 0, 0);
        }
        {
          int ccx = (it + 8) * 4 + quad;
          v8bf af = *(const v8bf*)((const char*)sm.hs + mr * 1024 + ((ccx ^ (mr & 7)) << 4));
          acc1 = __builtin_amdgcn_mfma_f32_16x16x32_bf16(af, breg[it + 8], acc1, 0, 0, 0);
        }
      }
      v4f acc = acc0 + acc1;
      if (n0 == 0 || l15 < 8) {
#pragma unroll
        for (int reg = 0; reg < 4; ++reg)
          sm.gh[(m0 + quad * 4 + reg) * 29 + n0 + l15] = acc[reg];
      }
    }
    __syncthreads();  // S1: gh ready

    // ---- combine gates; thread owns (batch cb, col c) ----
    float hn;
    {
      float ar = sm.gh[cb * 29 + j] + b_r;
      float az = sm.gh[cb * 29 + 8 + j] + b_z;
      float an = sm.gh[cb * 29 + 16 + j] + b_n;
      float rg = sigmoidf_(g_r + ar);
      float zg = sigmoidf_(g_z + az);
      float ng = tanhf(g_n + rg * an);
      hn = (1.f - zg) * ng + zg * hprev;
      hprev = hn;
      bf16 hb = (bf16)hn;
      sm.hnew[tid] = *(unsigned short*)&hb;
    }
    __syncthreads();  // S2: hnew ready (also WAR-protects gh/hs)

    // ---- global stores off the critical path (acks overlap exchange) ----
    rnn[((size_t)t * 32 + cb) * 512 + c] = hn;
    concat_bf[((size_t)t * 32 + cb) * CIN + c] = (bf16)hn;

    if (t < 63) {
      int target = t + 1;
      int p2 = target & 1;
      if (w == 0) {
        // publish: contiguous 512B burst (u64 idx = blk*64 + batch*2 + half)
        unsigned long long pk = *(const unsigned long long*)(sm.hnew + lane * 4);
        __hip_atomic_store(hx + (size_t)p2 * 4096 + blk * 64 + lane, pk,
                           __ATOMIC_RELAXED, __HIP_MEMORY_SCOPE_AGENT);
        asm volatile("s_waitcnt vmcnt(0)" ::: "memory");  // data at LLC before flag
        if (lane == 0)
          __hip_atomic_store(&bar[blk], target, __ATOMIC_RELAXED, __HIP_MEMORY_SCOPE_AGENT);
        // poll dense flags (4-line gather), s_sleep backoff
        for (;;) {
          int v = __hip_atomic_load(&bar[lane], __ATOMIC_RELAXED, __HIP_MEMORY_SCOPE_AGENT);
          if (__all(v >= target)) break;
          __builtin_amdgcn_s_sleep(1);
        }
        if (lane == 0) *(volatile int*)&sm.go = target;
      } else {
        while (*(volatile int*)&sm.go < target) __builtin_amdgcn_s_sleep(1);
      }

      // ---- bulk load: wave w instr i reads producer p=w*16+i contiguous ----
      {
        const unsigned long long* src = hx + (size_t)p2 * 4096 + w * 1024 + lane;
        unsigned long long vv[16];
#pragma unroll
        for (int i = 0; i < 16; ++i)
          vv[i] = __hip_atomic_load(src + i * 64, __ATOMIC_RELAXED, __HIP_MEMORY_SCOPE_AGENT);
#pragma unroll
        for (int i = 0; i < 16; ++i) {
          int p = w * 16 + i;       // producer block
          int bb = lane >> 1;       // batch row
          int half = lane & 1;
          *(unsigned long long*)((char*)sm.hs + bb * 1024 +
                                 (((p ^ (bb & 7)) << 4) | (half << 3))) = vv[i];
        }
      }
      __syncthreads();  // S3: hs(t+1) staged
    }
  }
}

// ---------------------------------------------------------------------------
// k_attnrow: per (n,b) row: a1,a3 dots + all three softmaxes -> aw1,aw2,aw3
// ---------------------------------------------------------------------------
__global__ __launch_bounds__(256) void k_attnrow(const float* __restrict__ rnn,
                                                 const float* __restrict__ misc,
                                                 float* __restrict__ aw1,
                                                 float* __restrict__ aw2,
                                                 float* __restrict__ aw3) {
  int wv = (blockIdx.x * 256 + threadIdx.x) >> 6;
  int lane = threadIdx.x & 63;
  if (wv >= 2048) return;
  int n = wv >> 5, b = wv & 31;
  const float* u1a = misc;
  const float* u3h = misc + 1024;
  const float* c1 = misc + 2560;
  const float* c2 = misc + 10752;
  const float* c3 = misc + 11776;
  const float* row = rnn + (size_t)(n * 32 + b) * 512;
  float s1 = 0.f, s3 = 0.f;
#pragma unroll
  for (int q = 0; q < 8; ++q) {
    int j = lane * 8 + q;
    float rv = row[j];
    s1 += rv * u1a[j];
    s3 += rv * u3h[j];
  }
  for (int o = 32; o > 0; o >>= 1) {
    s1 += __shfl_down(s1, o);
    s3 += __shfl_down(s3, o);
  }
  s1 = __shfl(s1, 0) + misc[1664];
  s3 = __shfl(s3, 0) + misc[1665];

  float e[4];
  float mx = -1e30f;
#pragma unroll
  for (int q = 0; q < 4; ++q) {
    int t = q * 64 + lane;
    e[q] = tanhf(s1 + c1[t * 32 + b]);
    mx = fmaxf(mx, e[q]);
  }
  for (int o = 32; o > 0; o >>= 1) mx = fmaxf(mx, __shfl_xor(mx, o));
  float sum = 0.f;
#pragma unroll
  for (int q = 0; q < 4; ++q) {
    e[q] = expf(e[q] - mx);
    sum += e[q];
  }
  for (int o = 32; o > 0; o >>= 1) sum += __shfl_xor(sum, o);
  float inv = 1.f / sum;
  size_t base1 = (size_t)(b * 64 + n) * 256;
#pragma unroll
  for (int q = 0; q < 4; ++q) aw1[base1 + q * 64 + lane] = e[q] * inv;

  float e2 = (lane < 32) ? tanhf(s1 + c2[lane * 32 + b]) : -1e30f;
  float m2 = e2;
  for (int o = 32; o > 0; o >>= 1) m2 = fmaxf(m2, __shfl_xor(m2, o));
  float x2 = (lane < 32) ? expf(e2 - m2) : 0.f;
  float sm2 = x2;
  for (int o = 32; o > 0; o >>= 1) sm2 += __shfl_xor(sm2, o);
  if (lane < 32) aw2[(size_t)(b * 64 + n) * 32 + lane] = x2 / sm2;

  float e3 = (lane < 5) ? tanhf(s3 + c3[lane * 32 + b]) : -1e30f;
  float m3 = e3;
  for (int o = 32; o > 0; o >>= 1) m3 = fmaxf(m3, __shfl_xor(m3, o));
  float x3 = (lane < 5) ? expf(e3 - m3) : 0.f;
  float sm3 = x3;
  for (int o = 32; o > 0; o >>= 1) sm3 += __shfl_xor(sm3, o);
  if (lane < 5) aw3[(size_t)(b * 64 + n) * 5 + lane] = x3 / sm3;
}

// ---------------------------------------------------------------------------
// k_ctx: ctx[n,b,col] = sum_te aw[b,n,te]*enc[te,b,col] -> bf16 into concat.
// ---------------------------------------------------------------------------
template <int TL, int COFF>
__global__ __launch_bounds__(256) void k_ctx(const float* __restrict__ aw,
                                             const float* __restrict__ enc,
                                             bf16* __restrict__ concat_bf) {
  __shared__ __align__(16) float awsT[TL * 36];
  int tid = threadIdx.x;
  int bx = blockIdx.x;
  int b = bx >> 2, q = (bx >> 1) & 1, nh = bx & 1;
  for (int i = tid; i < 32 * TL; i += 256) {
    int n = i / TL, te = i % TL;
    awsT[te * 36 + n] = aw[(size_t)b * 64 * TL + (size_t)(nh * 32 + n) * TL + te];
  }
  __syncthreads();
  int col = q * 256 + tid;
  float4 acc[8];
#pragma unroll
  for (int n4 = 0; n4 < 8; ++n4) acc[n4] = make_float4(0.f, 0.f, 0.f, 0.f);
  for (int te = 0; te < TL; ++te) {
    float v = enc[((size_t)te * 32 + b) * 512 + col];
#pragma unroll
    for (int n4 = 0; n4 < 8; ++n4) {
      float4 wv = *(const float4*)(awsT + te * 36 + n4 * 4);
      acc[n4].x += wv.x * v;
      acc[n4].y += wv.y * v;
      acc[n4].z += wv.z * v;
      acc[n4].w += wv.w * v;
    }
  }
#pragma unroll
  for (int n4 = 0; n4 < 8; ++n4) {
    int ng = nh * 32 + n4 * 4;
    concat_bf[((size_t)(ng + 0) * 32 + b) * CIN + COFF + col] = (bf16)acc[n4].x;
    concat_bf[((size_t)(ng + 1) * 32 + b) * CIN + COFF + col] = (bf16)acc[n4].y;
    concat_bf[((size_t)(ng + 2) * 32 + b) * CIN + COFF + col] = (bf16)acc[n4].z;
    concat_bf[((size_t)(ng + 3) * 32 + b) * CIN + COFF + col] = (bf16)acc[n4].w;
  }
}

// ---------------------------------------------------------------------------
// k_ctx3_misc: ctx3 (5-term) into concat cols [1536,1664) + hidden copy
// ---------------------------------------------------------------------------
__global__ void k_ctx3_misc(const float* __restrict__ aw3, const float* __restrict__ enc3,
                            const float* __restrict__ rnn, bf16* __restrict__ concat_bf,
                            float* __restrict__ hid) {
  int i = blockIdx.x * 256 + threadIdx.x;
  if (i < NB * 128) {
    int row = i >> 7, k = i & 127;
    int n = row >> 5, b = row & 31;
    float s = 0.f;
#pragma unroll
    for (int a = 0; a < 5; ++a)
      s += aw3[(size_t)(b * 64 + n) * 5 + a] * enc3[((size_t)a * 32 + b) * 128 + k];
    concat_bf[(size_t)row * CIN + 1536 + k] = (bf16)s;
  } else {
    int j = i - NB * 128;
    if (j < 16384) hid[j] = rnn[(size_t)63 * 16384 + j];
  }
}

// ---------------------------------------------------------------------------
// k_gate: gate[n,b,j] = tanh(gate_W[j,:] . [embedded, rnn, e4] + gate_b[j])
// ---------------------------------------------------------------------------
__global__ __launch_bounds__(256) void k_gate(const float* __restrict__ embedded,
                                              const float* __restrict__ rnn,
                                              const float* __restrict__ misc,
                                              const float* __restrict__ gW,
                                              const float* __restrict__ gb,
                                              float* __restrict__ gate) {
  int i = blockIdx.x * 256 + threadIdx.x;
  if (i >= NB * ANUMC) return;
  int row = i / ANUMC, j = i % ANUMC;
  int b = row & 31;
  const float* w = gW + (size_t)j * 1044;
  const float* e = embedded + (size_t)row * 512;
  const float* r = rnn + (size_t)row * 512;
  float s = gb[j];
#pragma unroll 4
  for (int k = 0; k < 512; k += 4) {
    float4 a = *(const float4*)(e + k);
    float4 ww = *(const float4*)(w + k);
    s += a.x * ww.x + a.y * ww.y + a.z * ww.z + a.w * ww.w;
  }
#pragma unroll 4
  for (int k = 0; k < 512; k += 4) {
    float4 a = *(const float4*)(r + k);
    float4 ww = *(const float4*)(w + 512 + k);
    s += a.x * ww.x + a.y * ww.y + a.z * ww.z + a.w * ww.w;
  }
  const float* e4 = misc + 1792 + b * ANUMC;
#pragma unroll
  for (int q = 0; q < ANUMC; ++q) s += w[1024 + q] * e4[q];
  gate[i] = tanhf(s);
}

// ---------------------------------------------------------------------------
// launcher
// ---------------------------------------------------------------------------
extern "C" void kernel_launch(void* const* d_in, const int* in_sizes, int n_in,
                              void* d_out, int out_size, void* d_ws, size_t ws_size,
                              hipStream_t stream) {
  const int* seq = (const int*)d_in[0];
  const float* lasth = (const float*)d_in[1];
  const float* enc1 = (const float*)d_in[2];
  const float* enc2 = (const float*)d_in[3];
  const float* enc3 = (const float*)d_in[4];
  const float* enc4 = (const float*)d_in[5];
  const int* aspect = (const int*)d_in[6];
  const float* emb = (const float*)d_in[7];
  const float* Wih = (const float*)d_in[8];
  const float* Whh = (const float*)d_in[9];
  const float* bih = (const float*)d_in[10];
  const float* bhh = (const float*)d_in[11];
  const float* attn_W = (const float*)d_in[12];
  const float* attn_b = (const float*)d_in[13];
  const float* attn_v = (const float*)d_in[14];
  const float* attr_W = (const float*)d_in[15];
  const float* attr_b = (const float*)d_in[16];
  const float* attr_v = (const float*)d_in[17];
  const float* cW = (const float*)d_in[18];
  const float* cbias = (const float*)d_in[19];
  const float* oW = (const float*)d_in[20];
  const float* ob = (const float*)d_in[21];
  const float* gW = (const float*)d_in[22];
  const float* gb = (const float*)d_in[23];
  const float* pW = (const float*)d_in[24];
  const float* pb = (const float*)d_in[25];

  char* ws = (char*)d_ws;
  float* misc = (float*)(ws + 0);                    // 64 KB
  float* embedded = (float*)(ws + 65536);            // 4 MB
  float* gi = (float*)(ws + 4259840);                // 12 MB (addtab/colnz after k_gru)
  float* rnn = (float*)(ws + 16842752);              // 4 MB
  bf16* emb_bf = (bf16*)(ws + 21037056);             // 2 MB
  bf16* Wih_bf = (bf16*)(ws + 23134208);             // 1.5 MB
  bf16* cW_bf = (bf16*)(ws + 24707072);              // 1.6 MB
  bf16* oW_bf = (bf16*)(ws + 26411008);              // 32.8 MB
  bf16* concat_bf = (bf16*)(ws + 59179008);          // 6.8 MB
  bf16* cout_bf = (bf16*)(ws + 65994752);            // 2 MB
  unsigned long long* hx = (unsigned long long*)(ws + 68091904);  // 64 KB h exchange (2 parities)
  int* bar = (int*)(misc + 12032);                   // 64 dense flags
  float* addtab = (float*)(ws + 4259840);            // 2.56 MB (reuses gi)
  int* colnz = (int*)(ws + 4259840 + 2560000);       // 128 KB

  float* out = (float*)d_out;
  float* hid_out = out + 65536000;
  float* aw1 = out + 65552384;
  float* aw2 = out + 66076672;
  float* aw3 = out + 66142208;
  float* gate = out + 66152448;

  k_zero<<<1, 64, 0, stream>>>(bar);
  k_vec<<<4, 256, 0, stream>>>(attn_W, attn_b, attn_v, attr_W, attr_b, attr_v, enc4, pW, pb, misc);
  k_embcvt<<<18624, 256, 0, stream>>>(seq, emb, embedded, emb_bf, Wih, Wih_bf, cW, cW_bf, oW,
                                      oW_bf);
  k_c<<<37, 256, 0, stream>>>(enc1, enc2, enc3, misc);
  k_gemm_bt<0><<<192, 256, 0, stream>>>(emb_bf, Wih_bf, bih, gi, nullptr, NB, G3H, 512,
                                        nullptr, nullptr, nullptr);
  k_gru<<<GB, 256, 0, stream>>>(gi, Whh, bhh, lasth, rnn, concat_bf, hx, bar);
  k_init0<<<2625, 256, 0, stream>>>(addtab, colnz);
  k_init1<<<1, 256, 0, stream>>>(aspect, addtab, colnz);
  k_attnrow<<<512, 256, 0, stream>>>(rnn, misc, aw1, aw2, aw3);
  k_ctx<256, 512><<<128, 256, 0, stream>>>(aw1, enc1, concat_bf);
  k_ctx<32, 1024><<<128, 256, 0, stream>>>(aw2, enc2, concat_bf);
  k_ctx3_misc<<<1088, 256, 0, stream>>>(aw3, enc3, rnn, concat_bf, hid_out);
  k_gate<<<160, 256, 0, stream>>>(embedded, rnn, misc, gW, gb, gate);
  k_gemm_bt<1><<<64, 256, 0, stream>>>(concat_bf, cW_bf, cbias, nullptr, cout_bf, NB,
                                       512, CIN, nullptr, nullptr, nullptr);
  k_gemm_bt<2><<<4000, 256, 0, stream>>>(cout_bf, oW_bf, ob, out, nullptr, NB, VOC, 512,
                                         addtab, colnz, gate);
}

// Round 7
// 1031.924 us; speedup vs baseline: 1.0668x; 1.0668x over previous
//
#include <hip/hip_runtime.h>
#include <hip/hip_bf16.h>

// ---------------------------------------------------------------------------
// Problem constants (from reference)
// ---------------------------------------------------------------------------
#define HDIM 512
#define KA   128
#define VOC  32000
#define ANUMC 20
#define NSEQ 64
#define BATCH 32
#define TLEN 256
#define SLEN 32
#define ALEN 5
#define NB   2048          // NSEQ*BATCH
#define CIN  1664          // 3H + KA
#define G3H  1536
#define GB   64            // GRU persistent blocks

typedef __bf16 bf16;
typedef bf16 v8bf __attribute__((ext_vector_type(8)));
typedef float v4f __attribute__((ext_vector_type(4)));

#define DEV __device__ __forceinline__

DEV float sigmoidf_(float x) { return 1.f / (1.f + expf(-x)); }

DEV unsigned long long pack4bf(float a, float b, float c, float d) {
  bf16 b0 = (bf16)a, b1 = (bf16)b, b2 = (bf16)c, b3 = (bf16)d;
  return (unsigned long long)*(unsigned short*)&b0 |
         ((unsigned long long)*(unsigned short*)&b1 << 16) |
         ((unsigned long long)*(unsigned short*)&b2 << 32) |
         ((unsigned long long)*(unsigned short*)&b3 << 48);
}

// ---------------------------------------------------------------------------
// k_zero: zero the GRU barrier flags (R3 layout: 64 flags x 128B own line --
// dense flags caused store-side false sharing across 64 blocks, R6 lesson)
// ---------------------------------------------------------------------------
__global__ void k_zero(int* bar) {
  for (int i = threadIdx.x; i < GB * 32; i += 256) bar[i] = 0;
}

// ---------------------------------------------------------------------------
// k_init0/k_init1: aspect-add table for the fused GEMM epilogue.
// ---------------------------------------------------------------------------
__global__ void k_init0(float* addtab, int* colnz) {
  int i = blockIdx.x * 256 + threadIdx.x;
  if (i < VOC * ANUMC) addtab[i] = 0.f;
  if (i < VOC) colnz[i] = 0;
}
__global__ void k_init1(const int* __restrict__ ids, float* addtab, int* colnz) {
  for (int k = threadIdx.x; k < 2000; k += 256) {
    int j = ids[k];
    atomicAdd(addtab + (size_t)j * ANUMC + (k % ANUMC), 1.0f);
    colnz[j] = 1;
  }
}

// ---------------------------------------------------------------------------
// k_vec: small precomputations (see earlier rounds)
// ---------------------------------------------------------------------------
__global__ void k_vec(const float* __restrict__ attn_W, const float* __restrict__ attn_b,
                      const float* __restrict__ attn_v,
                      const float* __restrict__ attr_W, const float* __restrict__ attr_b,
                      const float* __restrict__ attr_v,
                      const float* __restrict__ enc4, const float* __restrict__ pW,
                      const float* __restrict__ pb, float* __restrict__ misc) {
  int tid = threadIdx.x;
  int blk = blockIdx.x;
  if (blk == 0) {
    for (int i = tid; i < 512; i += 256) {
      float s = 0.f;
      for (int j = 0; j < 512; ++j) s += attn_W[j * 1024 + i] * attn_v[j];
      misc[i] = s;
    }
  } else if (blk == 1) {
    for (int i = tid; i < 512; i += 256) {
      float s = 0.f;
      for (int j = 0; j < 512; ++j) s += attn_W[j * 1024 + 512 + i] * attn_v[j];
      misc[512 + i] = s;
    }
  } else if (blk == 2) {
    for (int i = tid; i < 512; i += 256) {
      float s = 0.f;
      for (int j = 0; j < 512; ++j) s += attr_W[j * 640 + i] * attr_v[j];
      misc[1024 + i] = s;
    }
  } else {
    for (int i = tid; i < 128; i += 256) {
      float s = 0.f;
      for (int j = 0; j < 512; ++j) s += attr_W[j * 640 + 512 + i] * attr_v[j];
      misc[1536 + i] = s;
    }
    if (tid == 128) {
      float s = 0.f;
      for (int j = 0; j < 512; ++j) s += attn_b[j] * attn_v[j];
      misc[1664] = s;
    }
    if (tid == 129) {
      float s = 0.f;
      for (int j = 0; j < 512; ++j) s += attr_b[j] * attr_v[j];
      misc[1665] = s;
    }
    for (int i = tid; i < BATCH * ANUMC; i += 256) {
      int b = i / ANUMC, j = i % ANUMC;
      float s = pb[j];
      for (int q = 0; q < ANUMC; ++q) s += pW[j * 40 + q] * enc4[b * ANUMC + q];
      for (int q = 0; q < ANUMC; ++q) s += pW[j * 40 + 20 + q] * enc4[BATCH * ANUMC + b * ANUMC + q];
      misc[1792 + i] = s;
    }
  }
}

// ---------------------------------------------------------------------------
// k_embcvt: embedding gather + fp32->bf16 conversions, x4 vectorized
// ---------------------------------------------------------------------------
__global__ void k_embcvt(const int* __restrict__ seq, const float* __restrict__ emb,
                         float* __restrict__ embedded, bf16* __restrict__ emb_bf,
                         const float* __restrict__ Wih, bf16* __restrict__ Wih_bf,
                         const float* __restrict__ cW, bf16* __restrict__ cW_bf,
                         const float* __restrict__ oW, bf16* __restrict__ oW_bf) {
  size_t i = ((size_t)blockIdx.x * 256 + threadIdx.x) * 4;
  const size_t s0 = 1048576, s1 = s0 + 786432, s2 = s1 + 851968, s3 = s2 + 16384000;
  if (i < s0) {
    int row = (int)(i >> 9), col = (int)(i & 511);
    float4 v = *(const float4*)(emb + (size_t)seq[row] * 512 + col);
    *(float4*)(embedded + i) = v;
    *(unsigned long long*)(emb_bf + i) = pack4bf(v.x, v.y, v.z, v.w);
  } else if (i < s1) {
    size_t j = i - s0;
    float4 v = *(const float4*)(Wih + j);
    *(unsigned long long*)(Wih_bf + j) = pack4bf(v.x, v.y, v.z, v.w);
  } else if (i < s2) {
    size_t j = i - s1;
    float4 v = *(const float4*)(cW + j);
    *(unsigned long long*)(cW_bf + j) = pack4bf(v.x, v.y, v.z, v.w);
  } else if (i < s3) {
    size_t j = i - s2;
    float4 v = *(const float4*)(oW + j);
    *(unsigned long long*)(oW_bf + j) = pack4bf(v.x, v.y, v.z, v.w);
  }
}

// ---------------------------------------------------------------------------
// k_c: c1[t*32+b] = enc1[t,b,:] . u1e ; c2 (enc2, u1e) ; c3 (enc3, u3e)
// ---------------------------------------------------------------------------
__global__ void k_c(const float* __restrict__ enc1, const float* __restrict__ enc2,
                    const float* __restrict__ enc3, float* __restrict__ misc) {
  int i = blockIdx.x * 256 + threadIdx.x;
  const float* u1e = misc + 512;
  const float* u3e = misc + 1536;
  if (i < 8192) {
    const float* row = enc1 + (size_t)i * 512;
    float s = 0.f;
#pragma unroll 4
    for (int j = 0; j < 512; j += 4) {
      float4 a = *(const float4*)(row + j);
      float4 u = *(const float4*)(u1e + j);
      s += a.x * u.x + a.y * u.y + a.z * u.z + a.w * u.w;
    }
    misc[2560 + i] = s;
  } else if (i < 8192 + 1024) {
    int k = i - 8192;
    const float* row = enc2 + (size_t)k * 512;
    float s = 0.f;
#pragma unroll 4
    for (int j = 0; j < 512; j += 4) {
      float4 a = *(const float4*)(row + j);
      float4 u = *(const float4*)(u1e + j);
      s += a.x * u.x + a.y * u.y + a.z * u.z + a.w * u.w;
    }
    misc[10752 + k] = s;
  } else if (i < 8192 + 1024 + 160) {
    int k = i - 9216;
    const float* row = enc3 + (size_t)k * 128;
    float s = 0.f;
#pragma unroll 4
    for (int j = 0; j < 128; j += 4) {
      float4 a = *(const float4*)(row + j);
      float4 u = *(const float4*)(u3e + j);
      s += a.x * u.x + a.y * u.y + a.z * u.z + a.w * u.w;
    }
    misc[11776 + k] = s;
  }
}

// ---------------------------------------------------------------------------
// Generic NT GEMM (round-3 tuned; round-7: min-waves hint 2 -> 4 to lift
// co-resident blocks/CU -- VGPR 100 < 128 cap, no spill risk)
// ---------------------------------------------------------------------------
template <int EPI>
__global__ __launch_bounds__(256, 4) void k_gemm_bt(const bf16* __restrict__ A,
                                                    const bf16* __restrict__ Bm,
                                                    const float* __restrict__ bias,
                                                    float* __restrict__ Cf, bf16* __restrict__ Cb,
                                                    int M, int Nn, int Kd,
                                                    const float* __restrict__ addtab,
                                                    const int* __restrict__ colnz,
                                                    const float* __restrict__ gate) {
  __shared__ __align__(16) unsigned short As[128 * 64];
  __shared__ __align__(16) unsigned short Bs[128 * 64];
  int tid = threadIdx.x;
  int nwg = gridDim.x;
  int cpx = nwg >> 3;
  int wgid = (blockIdx.x & 7) * cpx + (blockIdx.x >> 3);
  int MT = M >> 7;
  int m0 = (wgid % MT) << 7;
  int n0 = (wgid / MT) << 7;
  int lane = tid & 63;
  int wv = tid >> 6;
  int wm = wv & 1, wn = wv >> 1;
  int l15 = lane & 15, quad = lane >> 4;
  int l8r = lane >> 3;
  int lp = lane & 7;

  v4f acc[4][4];
#pragma unroll
  for (int i = 0; i < 4; ++i)
#pragma unroll
    for (int j = 0; j < 4; ++j) acc[i][j] = (v4f){0.f, 0.f, 0.f, 0.f};

  for (int kb = 0; kb < Kd; kb += 64) {
#pragma unroll
    for (int r = 0; r < 4; ++r) {
      int g = wv * 4 + r;
      int lr = g * 8 + l8r;
      int ca = (lp ^ (lr & 7)) * 8;
      __builtin_amdgcn_global_load_lds(
          (const __attribute__((address_space(1))) void*)(A + (size_t)(m0 + lr) * Kd + kb + ca),
          (__attribute__((address_space(3))) void*)((char*)As + g * 1024), 16, 0, 0);
      __builtin_amdgcn_global_load_lds(
          (const __attribute__((address_space(1))) void*)(Bm + (size_t)(n0 + lr) * Kd + kb + ca),
          (__attribute__((address_space(3))) void*)((char*)Bs + g * 1024), 16, 0, 0);
    }
    __syncthreads();
#pragma unroll
    for (int ks = 0; ks < 2; ++ks) {
      v8bf af[4], bfr[4];
      int c = ks * 4 + quad;
#pragma unroll
      for (int i = 0; i < 4; ++i) {
        int mr = wm * 64 + i * 16 + l15;
        af[i] = *(const v8bf*)((const char*)As + mr * 128 + ((c ^ (mr & 7)) << 4));
      }
#pragma unroll
      for (int j = 0; j < 4; ++j) {
        int nr = wn * 64 + j * 16 + l15;
        bfr[j] = *(const v8bf*)((const char*)Bs + nr * 128 + ((c ^ (nr & 7)) << 4));
      }
#pragma unroll
      for (int i = 0; i < 4; ++i)
#pragma unroll
        for (int j = 0; j < 4; ++j)
          acc[i][j] = __builtin_amdgcn_mfma_f32_16x16x32_bf16(af[i], bfr[j], acc[i][j], 0, 0, 0);
    }
    __syncthreads();
  }
#pragma unroll
  for (int i = 0; i < 4; ++i) {
    int gr0 = m0 + wm * 64 + i * 16 + quad * 4;
#pragma unroll
    for (int j = 0; j < 4; ++j) {
      int gc = n0 + wn * 64 + j * 16 + l15;
      float bs = bias[gc];
      if (EPI == 2) {
        int nz = colnz[gc];
        float ar[ANUMC];
        if (nz) {
#pragma unroll
          for (int a = 0; a < ANUMC; ++a) ar[a] = addtab[(size_t)gc * ANUMC + a];
        }
#pragma unroll
        for (int reg = 0; reg < 4; ++reg) {
          float v = acc[i][j][reg] + bs;
          if (nz) {
            const float* gr = gate + (size_t)(gr0 + reg) * ANUMC;
#pragma unroll
            for (int a = 0; a < ANUMC; ++a) v += ar[a] * gr[a];
          }
          Cf[(size_t)(gr0 + reg) * Nn + gc] = v;
        }
      } else {
#pragma unroll
        for (int reg = 0; reg < 4; ++reg) {
          float v = acc[i][j][reg] + bs;
          if (EPI == 1)
            Cb[(size_t)(gr0 + reg) * Nn + gc] = (bf16)tanhf(v);
          else
            Cf[(size_t)(gr0 + reg) * Nn + gc] = v;
        }
      }
    }
  }
}

// ---------------------------------------------------------------------------
// k_gru: EXACT round-3 verified configuration (211 us measured).
// R4 (fragment-direct gather), R5 (role-split + no-sleep spin), R6 (dense
// flags) all regressed: scattered-gather doubles coherent line count; multi-
// wave spin floods the LLC coherent path; dense flags false-share on stores.
// Keep: Whh in registers; wave0-only publish (scatter) + wave-local vmcnt
// drain + per-128B-line flag; wave0 poll w/ s_sleep + LDS go broadcast;
// 4-wave coalesced bulk load into XOR-swizzled LDS; parity double buffer.
// ---------------------------------------------------------------------------
__global__ __launch_bounds__(256) void k_gru(const float* __restrict__ gi,
                                             const float* __restrict__ Whh,
                                             const float* __restrict__ bhh,
                                             const float* __restrict__ lasth,
                                             float* __restrict__ rnn,
                                             bf16* __restrict__ concat_bf,
                                             unsigned long long* __restrict__ hx,
                                             int* __restrict__ bar) {
  struct SMEM {
    unsigned short hs[32 * 512];   // 32 KB, XOR-swizzled
    float gh[32 * 29];             // 3.7 KB (stride 29: conflict-free acc writes)
    unsigned short hnew[256];      // 8B-aligned
    int go;                        // wave0 -> others handoff
  };
  __shared__ __align__(16) SMEM sm;
  int tid = threadIdx.x;
  int blk = blockIdx.x;
  int c0 = blk * 8;

  int lane = tid & 63;
  int w = tid >> 6;
  int l15 = lane & 15, quad = lane >> 4;
  int m0 = (w & 1) * 16;   // batch tile
  int n0 = (w >> 1) * 16;  // gate-row tile (rows >=24 phantom)

  if (tid == 0) sm.go = 0;

  // ---- Whh B-fragments -> registers (held across all 64 steps) ----
  v8bf breg[16];
  {
    int nr = n0 + l15;
    if (nr > 23) nr = 23;
    const float* wrow = Whh + (size_t)((nr >> 3) * 512 + c0 + (nr & 7)) * 512;
#pragma unroll
    for (int it = 0; it < 16; ++it) {
      int k0 = it * 32 + quad * 8;
      float4 x = *(const float4*)(wrow + k0);
      float4 y = *(const float4*)(wrow + k0 + 4);
      v8bf vv;
      vv[0] = (bf16)x.x; vv[1] = (bf16)x.y; vv[2] = (bf16)x.z; vv[3] = (bf16)x.w;
      vv[4] = (bf16)y.x; vv[5] = (bf16)y.y; vv[6] = (bf16)y.z; vv[7] = (bf16)y.w;
      breg[it] = vv;
    }
  }

  // ---- stage h(0) = lasth into LDS (all threads) ----
#pragma unroll
  for (int rnd = 0; rnd < 8; ++rnd) {
    int ch = rnd * 256 + tid;
    int bb = ch >> 6, cc = ch & 63;
    const float* hp = lasth + bb * 512 + cc * 8;
    float4 x = *(const float4*)hp;
    float4 y = *(const float4*)(hp + 4);
    v8bf vv;
    vv[0] = (bf16)x.x; vv[1] = (bf16)x.y; vv[2] = (bf16)x.z; vv[3] = (bf16)x.w;
    vv[4] = (bf16)y.x; vv[5] = (bf16)y.y; vv[6] = (bf16)y.z; vv[7] = (bf16)y.w;
    *(v8bf*)((char*)sm.hs + bb * 1024 + ((cc ^ (bb & 7)) << 4)) = vv;
  }

  int cb = tid >> 3, j = tid & 7, c = c0 + j;
  float hprev = lasth[cb * 512 + c];
  float b_r = bhh[c], b_z = bhh[512 + c], b_n = bhh[1024 + c];
  __syncthreads();

  for (int t = 0; t < 64; ++t) {
    // prefetch this step's gi (independent of h; hides under MFMA)
    const float* gii = gi + ((size_t)t * 32 + cb) * G3H;
    float g_r = gii[c];
    float g_z = gii[512 + c];
    float g_n = gii[1024 + c];

    // ---- MFMA: gh[batch 32][gaterow 24]; A from LDS, B from registers ----
    {
      v4f acc0 = (v4f){0.f, 0.f, 0.f, 0.f};
      v4f acc1 = (v4f){0.f, 0.f, 0.f, 0.f};
      int mr = m0 + l15;
#pragma unroll
      for (int it = 0; it < 8; ++it) {
        {
          int ccx = it * 4 + quad;
          v8bf af = *(const v8bf*)((const char*)sm.hs + mr * 1024 + ((ccx ^ (mr & 7)) << 4));
          acc0 = __builtin_amdgcn_mfma_f32_16x16x32_bf16(af, breg[it], acc0, 0, 0, 0);
        }
        {
          int ccx = (it + 8) * 4 + quad;
          v8bf af = *(const v8bf*)((const char*)sm.hs + mr * 1024 + ((ccx ^ (mr & 7)) << 4));
          acc1 = __builtin_amdgcn_mfma_f32_16x16x32_bf16(af, breg[it + 8], acc1, 0, 0, 0);
        }
      }
      v4f acc = acc0 + acc1;
      if (n0 == 0 || l15 < 8) {
#pragma unroll
        for (int reg = 0; reg < 4; ++reg)
          sm.gh[(m0 + quad * 4 + reg) * 29 + n0 + l15] = acc[reg];
      }
    }
    __syncthreads();

    // ---- combine gates; thread owns (batch cb, col c) ----
    {
      float ar = sm.gh[cb * 29 + j] + b_r;
      float az = sm.gh[cb * 29 + 8 + j] + b_z;
      float an = sm.gh[cb * 29 + 16 + j] + b_n;
      float rg = sigmoidf_(g_r + ar);
      float zg = sigmoidf_(g_z + az);
      float ng = tanhf(g_n + rg * an);
      float hn = (1.f - zg) * ng + zg * hprev;
      hprev = hn;
      rnn[((size_t)t * 32 + cb) * 512 + c] = hn;
      bf16 hb = (bf16)hn;
      concat_bf[((size_t)t * 32 + cb) * CIN + c] = hb;
      sm.hnew[tid] = *(unsigned short*)&hb;
    }

    if (t < 63) {
      __syncthreads();  // hnew complete in LDS (also orders hs reuse below)
      int target = t + 1;
      int pnext = target & 1;
      if (w == 0) {
        // publish: lane q packs hnew[4q..4q+3] (= h[q>>1][c0+(q&1)*4 ..+3])
        unsigned long long pk = *(const unsigned long long*)(sm.hnew + lane * 4);
        int wd = (lane >> 1) * 128 + blk * 2 + (lane & 1);
        __hip_atomic_store(hx + (size_t)pnext * 4096 + wd, pk,
                           __ATOMIC_RELAXED, __HIP_MEMORY_SCOPE_AGENT);
        // wave-local drain: data at LLC before flag issues
        asm volatile("s_waitcnt vmcnt(0)" ::: "memory");
        if (lane == 0)
          __hip_atomic_store(&bar[blk * 32], target, __ATOMIC_RELAXED,
                             __HIP_MEMORY_SCOPE_AGENT);
        // poll all 64 flags
        for (;;) {
          int v = __hip_atomic_load(&bar[lane * 32], __ATOMIC_RELAXED,
                                    __HIP_MEMORY_SCOPE_AGENT);
          if (__all(v >= target)) break;
          __builtin_amdgcn_s_sleep(1);
        }
        if (lane == 0) *(volatile int*)&sm.go = target;
      } else {
        while (*(volatile int*)&sm.go < target) __builtin_amdgcn_s_sleep(1);
      }

      // ---- bulk load this wave's 8 batches (8KB) -> swizzled LDS ----
      {
        const unsigned long long* src = hx + (size_t)pnext * 4096 + w * 1024 + lane;
        unsigned long long vv[16];
#pragma unroll
        for (int i = 0; i < 16; ++i)
          vv[i] = __hip_atomic_load(src + i * 64, __ATOMIC_RELAXED,
                                    __HIP_MEMORY_SCOPE_AGENT);
#pragma unroll
        for (int i = 0; i < 16; ++i) {
          int W = w * 1024 + i * 64 + lane;
          int bb = W >> 7, wr = W & 127;
          int u = wr >> 1, half = wr & 1;
          *(unsigned long long*)((char*)sm.hs + bb * 1024 +
                                 (((u ^ (bb & 7)) << 4) | (half << 3))) = vv[i];
        }
      }
      __syncthreads();  // hs staged by all waves
    }
  }
}

// ---------------------------------------------------------------------------
// k_attnrow: per (n,b) row: a1,a3 dots + all three softmaxes -> aw1,aw2,aw3
// ---------------------------------------------------------------------------
__global__ __launch_bounds__(256) void k_attnrow(const float* __restrict__ rnn,
                                                 const float* __restrict__ misc,
                                                 float* __restrict__ aw1,
                                                 float* __restrict__ aw2,
                                                 float* __restrict__ aw3) {
  int wv = (blockIdx.x * 256 + threadIdx.x) >> 6;
  int lane = threadIdx.x & 63;
  if (wv >= 2048) return;
  int n = wv >> 5, b = wv & 31;
  const float* u1a = misc;
  const float* u3h = misc + 1024;
  const float* c1 = misc + 2560;
  const float* c2 = misc + 10752;
  const float* c3 = misc + 11776;
  const float* row = rnn + (size_t)(n * 32 + b) * 512;
  float s1 = 0.f, s3 = 0.f;
#pragma unroll
  for (int q = 0; q < 8; ++q) {
    int j = lane * 8 + q;
    float rv = row[j];
    s1 += rv * u1a[j];
    s3 += rv * u3h[j];
  }
  for (int o = 32; o > 0; o >>= 1) {
    s1 += __shfl_down(s1, o);
    s3 += __shfl_down(s3, o);
  }
  s1 = __shfl(s1, 0) + misc[1664];
  s3 = __shfl(s3, 0) + misc[1665];

  float e[4];
  float mx = -1e30f;
#pragma unroll
  for (int q = 0; q < 4; ++q) {
    int t = q * 64 + lane;
    e[q] = tanhf(s1 + c1[t * 32 + b]);
    mx = fmaxf(mx, e[q]);
  }
  for (int o = 32; o > 0; o >>= 1) mx = fmaxf(mx, __shfl_xor(mx, o));
  float sum = 0.f;
#pragma unroll
  for (int q = 0; q < 4; ++q) {
    e[q] = expf(e[q] - mx);
    sum += e[q];
  }
  for (int o = 32; o > 0; o >>= 1) sum += __shfl_xor(sum, o);
  float inv = 1.f / sum;
  size_t base1 = (size_t)(b * 64 + n) * 256;
#pragma unroll
  for (int q = 0; q < 4; ++q) aw1[base1 + q * 64 + lane] = e[q] * inv;

  float e2 = (lane < 32) ? tanhf(s1 + c2[lane * 32 + b]) : -1e30f;
  float m2 = e2;
  for (int o = 32; o > 0; o >>= 1) m2 = fmaxf(m2, __shfl_xor(m2, o));
  float x2 = (lane < 32) ? expf(e2 - m2) : 0.f;
  float sm2 = x2;
  for (int o = 32; o > 0; o >>= 1) sm2 += __shfl_xor(sm2, o);
  if (lane < 32) aw2[(size_t)(b * 64 + n) * 32 + lane] = x2 / sm2;

  float e3 = (lane < 5) ? tanhf(s3 + c3[lane * 32 + b]) : -1e30f;
  float m3 = e3;
  for (int o = 32; o > 0; o >>= 1) m3 = fmaxf(m3, __shfl_xor(m3, o));
  float x3 = (lane < 5) ? expf(e3 - m3) : 0.f;
  float sm3 = x3;
  for (int o = 32; o > 0; o >>= 1) sm3 += __shfl_xor(sm3, o);
  if (lane < 5) aw3[(size_t)(b * 64 + n) * 5 + lane] = x3 / sm3;
}

// ---------------------------------------------------------------------------
// k_ctx: ctx[n,b,col] = sum_te aw[b,n,te]*enc[te,b,col] -> bf16 into concat.
// ---------------------------------------------------------------------------
template <int TL, int COFF>
__global__ __launch_bounds__(256) void k_ctx(const float* __restrict__ aw,
                                             const float* __restrict__ enc,
                                             bf16* __restrict__ concat_bf) {
  __shared__ __align__(16) float awsT[TL * 36];
  int tid = threadIdx.x;
  int bx = blockIdx.x;
  int b = bx >> 2, q = (bx >> 1) & 1, nh = bx & 1;
  for (int i = tid; i < 32 * TL; i += 256) {
    int n = i / TL, te = i % TL;
    awsT[te * 36 + n] = aw[(size_t)b * 64 * TL + (size_t)(nh * 32 + n) * TL + te];
  }
  __syncthreads();
  int col = q * 256 + tid;
  float4 acc[8];
#pragma unroll
  for (int n4 = 0; n4 < 8; ++n4) acc[n4] = make_float4(0.f, 0.f, 0.f, 0.f);
  for (int te = 0; te < TL; ++te) {
    float v = enc[((size_t)te * 32 + b) * 512 + col];
#pragma unroll
    for (int n4 = 0; n4 < 8; ++n4) {
      float4 wv = *(const float4*)(awsT + te * 36 + n4 * 4);
      acc[n4].x += wv.x * v;
      acc[n4].y += wv.y * v;
      acc[n4].z += wv.z * v;
      acc[n4].w += wv.w * v;
    }
  }
#pragma unroll
  for (int n4 = 0; n4 < 8; ++n4) {
    int ng = nh * 32 + n4 * 4;
    concat_bf[((size_t)(ng + 0) * 32 + b) * CIN + COFF + col] = (bf16)acc[n4].x;
    concat_bf[((size_t)(ng + 1) * 32 + b) * CIN + COFF + col] = (bf16)acc[n4].y;
    concat_bf[((size_t)(ng + 2) * 32 + b) * CIN + COFF + col] = (bf16)acc[n4].z;
    concat_bf[((size_t)(ng + 3) * 32 + b) * CIN + COFF + col] = (bf16)acc[n4].w;
  }
}

// ---------------------------------------------------------------------------
// k_ctx3_misc: ctx3 (5-term) into concat cols [1536,1664) + hidden copy
// ---------------------------------------------------------------------------
__global__ void k_ctx3_misc(const float* __restrict__ aw3, const float* __restrict__ enc3,
                            const float* __restrict__ rnn, bf16* __restrict__ concat_bf,
                            float* __restrict__ hid) {
  int i = blockIdx.x * 256 + threadIdx.x;
  if (i < NB * 128) {
    int row = i >> 7, k = i & 127;
    int n = row >> 5, b = row & 31;
    float s = 0.f;
#pragma unroll
    for (int a = 0; a < 5; ++a)
      s += aw3[(size_t)(b * 64 + n) * 5 + a] * enc3[((size_t)a * 32 + b) * 128 + k];
    concat_bf[(size_t)row * CIN + 1536 + k] = (bf16)s;
  } else {
    int j = i - NB * 128;
    if (j < 16384) hid[j] = rnn[(size_t)63 * 16384 + j];
  }
}

// ---------------------------------------------------------------------------
// k_gate: gate[n,b,j] = tanh(gate_W[j,:] . [embedded, rnn, e4] + gate_b[j])
// ---------------------------------------------------------------------------
__global__ __launch_bounds__(256) void k_gate(const float* __restrict__ embedded,
                                              const float* __restrict__ rnn,
                                              const float* __restrict__ misc,
                                              const float* __restrict__ gW,
                                              const float* __restrict__ gb,
                                              float* __restrict__ gate) {
  int i = blockIdx.x * 256 + threadIdx.x;
  if (i >= NB * ANUMC) return;
  int row = i / ANUMC, j = i % ANUMC;
  int b = row & 31;
  const float* w = gW + (size_t)j * 1044;
  const float* e = embedded + (size_t)row * 512;
  const float* r = rnn + (size_t)row * 512;
  float s = gb[j];
#pragma unroll 4
  for (int k = 0; k < 512; k += 4) {
    float4 a = *(const float4*)(e + k);
    float4 ww = *(const float4*)(w + k);
    s += a.x * ww.x + a.y * ww.y + a.z * ww.z + a.w * ww.w;
  }
#pragma unroll 4
  for (int k = 0; k < 512; k += 4) {
    float4 a = *(const float4*)(r + k);
    float4 ww = *(const float4*)(w + 512 + k);
    s += a.x * ww.x + a.y * ww.y + a.z * ww.z + a.w * ww.w;
  }
  const float* e4 = misc + 1792 + b * ANUMC;
#pragma unroll
  for (int q = 0; q < ANUMC; ++q) s += w[1024 + q] * e4[q];
  gate[i] = tanhf(s);
}

// ---------------------------------------------------------------------------
// launcher
// ---------------------------------------------------------------------------
extern "C" void kernel_launch(void* const* d_in, const int* in_sizes, int n_in,
                              void* d_out, int out_size, void* d_ws, size_t ws_size,
                              hipStream_t stream) {
  const int* seq = (const int*)d_in[0];
  const float* lasth = (const float*)d_in[1];
  const float* enc1 = (const float*)d_in[2];
  const float* enc2 = (const float*)d_in[3];
  const float* enc3 = (const float*)d_in[4];
  const float* enc4 = (const float*)d_in[5];
  const int* aspect = (const int*)d_in[6];
  const float* emb = (const float*)d_in[7];
  const float* Wih = (const float*)d_in[8];
  const float* Whh = (const float*)d_in[9];
  const float* bih = (const float*)d_in[10];
  const float* bhh = (const float*)d_in[11];
  const float* attn_W = (const float*)d_in[12];
  const float* attn_b = (const float*)d_in[13];
  const float* attn_v = (const float*)d_in[14];
  const float* attr_W = (const float*)d_in[15];
  const float* attr_b = (const float*)d_in[16];
  const float* attr_v = (const float*)d_in[17];
  const float* cW = (const float*)d_in[18];
  const float* cbias = (const float*)d_in[19];
  const float* oW = (const float*)d_in[20];
  const float* ob = (const float*)d_in[21];
  const float* gW = (const float*)d_in[22];
  const float* gb = (const float*)d_in[23];
  const float* pW = (const float*)d_in[24];
  const float* pb = (const float*)d_in[25];

  char* ws = (char*)d_ws;
  float* misc = (float*)(ws + 0);                    // 64 KB
  float* embedded = (float*)(ws + 65536);            // 4 MB
  float* gi = (float*)(ws + 4259840);                // 12 MB (addtab/colnz after k_gru)
  float* rnn = (float*)(ws + 16842752);              // 4 MB
  bf16* emb_bf = (bf16*)(ws + 21037056);             // 2 MB
  bf16* Wih_bf = (bf16*)(ws + 23134208);             // 1.5 MB
  bf16* cW_bf = (bf16*)(ws + 24707072);              // 1.6 MB
  bf16* oW_bf = (bf16*)(ws + 26411008);              // 32.8 MB
  bf16* concat_bf = (bf16*)(ws + 59179008);          // 6.8 MB
  bf16* cout_bf = (bf16*)(ws + 65994752);            // 2 MB
  unsigned long long* hx = (unsigned long long*)(ws + 68091904);  // 64 KB h exchange (2 parities)
  int* bar = (int*)(misc + 12032);                   // 64 flags x 128B (own line each)
  float* addtab = (float*)(ws + 4259840);            // 2.56 MB (reuses gi)
  int* colnz = (int*)(ws + 4259840 + 2560000);       // 128 KB

  float* out = (float*)d_out;
  float* hid_out = out + 65536000;
  float* aw1 = out + 65552384;
  float* aw2 = out + 66076672;
  float* aw3 = out + 66142208;
  float* gate = out + 66152448;

  k_zero<<<1, 256, 0, stream>>>(bar);
  k_vec<<<4, 256, 0, stream>>>(attn_W, attn_b, attn_v, attr_W, attr_b, attr_v, enc4, pW, pb, misc);
  k_embcvt<<<18624, 256, 0, stream>>>(seq, emb, embedded, emb_bf, Wih, Wih_bf, cW, cW_bf, oW,
                                      oW_bf);
  k_c<<<37, 256, 0, stream>>>(enc1, enc2, enc3, misc);
  k_gemm_bt<0><<<192, 256, 0, stream>>>(emb_bf, Wih_bf, bih, gi, nullptr, NB, G3H, 512,
                                        nullptr, nullptr, nullptr);
  k_gru<<<GB, 256, 0, stream>>>(gi, Whh, bhh, lasth, rnn, concat_bf, hx, bar);
  k_init0<<<2625, 256, 0, stream>>>(addtab, colnz);
  k_init1<<<1, 256, 0, stream>>>(aspect, addtab, colnz);
  k_attnrow<<<512, 256, 0, stream>>>(rnn, misc, aw1, aw2, aw3);
  k_ctx<256, 512><<<128, 256, 0, stream>>>(aw1, enc1, concat_bf);
  k_ctx<32, 1024><<<128, 256, 0, stream>>>(aw2, enc2, concat_bf);
  k_ctx3_misc<<<1088, 256, 0, stream>>>(aw3, enc3, rnn, concat_bf, hid_out);
  k_gate<<<160, 256, 0, stream>>>(embedded, rnn, misc, gW, gb, gate);
  k_gemm_bt<1><<<64, 256, 0, stream>>>(concat_bf, cW_bf, cbias, nullptr, cout_bf, NB,
                                       512, CIN, nullptr, nullptr, nullptr);
  k_gemm_bt<2><<<4000, 256, 0, stream>>>(cout_bf, oW_bf, ob, out, nullptr, NB, VOC, 512,
                                         addtab, colnz, gate);
}